// Round 13
// baseline (310.197 us; speedup 1.0000x reference)
//
#include <hip/hip_runtime.h>

#define NPTS 300000
#define LOG2T 19
#define TSIZE (1u<<LOG2T)
#define NROWS 300032u          // = 1172 * 256
#define BLKS_PER_LV 1172u

typedef float f32x4 __attribute__((ext_vector_type(4)));
typedef __bf16 bf16x8 __attribute__((ext_vector_type(8)));

__device__ __forceinline__ unsigned short f2bf(float f){
  unsigned u = __builtin_bit_cast(unsigned, f);
  u += 0x7fffu + ((u>>16)&1u);          // round-to-nearest-even
  return (unsigned short)(u>>16);
}
__device__ __forceinline__ float bf_lo(unsigned v){ return __builtin_bit_cast(float, v<<16); }
__device__ __forceinline__ float bf_hi(unsigned v){ return __builtin_bit_cast(float, v&0xffff0000u); }

__device__ __forceinline__ unsigned qsel(uint4 q, unsigned i){
  unsigned lo = (i&1u) ? q.y : q.x;
  unsigned hi = (i&1u) ? q.w : q.z;
  return (i&2u) ? hi : lo;
}

// tau-scramble of the K dimension: makes the C->B fragment handoff lane-local.
// B slot (kt,q,t,j) consumes K-row 32kt+8q+2t+j; C slot (mt,q,rr) produces
// neuron 16mt+4q+rr. tau(32kt+8q+2t+j) = 16(2kt+j)+4q+t aligns them.
__device__ __forceinline__ int tau(int k){
  return 16*(2*(k>>5) + (k&1)) + 4*((k>>3)&3) + ((k>>1)&3);
}

// ---------------- prep: weights f32->bf16 frags + table f32->packed bf16 -----
struct WP { const float* p[17]; };

__device__ const int LK[17]  = {32,64, 64,64,64, 64,64,64, 64,64,64, 64,64,64, 64,64,64};
__device__ const int LN[17]  = {64,64, 64,64, 3, 64,64, 3, 64,64, 4, 64,64, 1, 64,64,48};
__device__ const int LNT[17] = { 4, 4,  4, 4, 1,  4, 4, 1,  4, 4, 1,  4, 4, 1,  4, 4, 3};
__device__ const int LOFF[17]= {0,4096, 12288,20480,28672, 30720,38912,47104,
                                49152,57344,65536, 67584,75776,83968, 86016,94208,102400};

__global__ void prep_all(WP wp, unsigned short* wdst,
                         const float* __restrict__ t, unsigned* __restrict__ tdst){
  int gtid = blockIdx.x*blockDim.x + threadIdx.x;
  int gstr = blockDim.x*gridDim.x;
  if(tdst){
    int n = (16 << LOG2T) / 2;  // 4M float4 -> uint2
    for(int i=gtid; i<n; i+=gstr){
      float4 f = ((const float4*)t)[i];
      uint2 o;
      o.x = (unsigned)f2bf(f.x) | ((unsigned)f2bf(f.y)<<16);
      o.y = (unsigned)f2bf(f.z) | ((unsigned)f2bf(f.w)<<16);
      ((uint2*)tdst)[i] = o;
    }
  }
  for(int layer=0; layer<17; layer++){
    const float* W = wp.p[layer];
    int K = LK[layer], Nn = LN[layer], NT = LNT[layer];
    unsigned short* d = wdst + LOFF[layer]/2;
    int nel = (K/32) * NT * 512;
    for(int i=gtid; i<nel; i += gstr){
      int j = i & 7, l = (i>>3)&63, fidx = i>>9;
      int kt = fidx / NT, nt = fidx - kt*NT;
      int k = kt*32 + ((l>>4)<<3) + j;
      if(layer != 0) k = tau(k);          // K-scramble (all K=64 layers)
      int n = nt*16 + (l&15);
      unsigned short v = 0;
      if(n < Nn) v = f2bf(W[k*Nn + n]);
      d[i] = v;
    }
  }
}

// ---------------- encode: one thread per (point, level), level-major blocks --
// quad x-pair trick (PRIMES[0]==1): h1 = h0 ^ d with d = i0^(i0+1); when d<=3
// (75% of i0) both x-corners live in one aligned uint4 -> 8 quad loads; only
// i0 % 4 == 3 lanes issue the 8 scalar fallbacks. ~10 requests vs 16 naive.
template<bool BT>
__global__ __launch_bounds__(256) void encode_lv(
    const float* __restrict__ xyz, const float* __restrict__ timep,
    const float* __restrict__ bmin, const float* __restrict__ bmax,
    const void* __restrict__ tab, unsigned* __restrict__ enc_t)
{
  unsigned bid = blockIdx.x;
  unsigned lv = bid / BLKS_PER_LV;
  unsigned p = (bid - lv*BLKS_PER_LV)*256u + threadIdx.x;
  size_t oidx = (size_t)lv*NROWS + p;
  if(p >= NPTS){ enc_t[oidx] = 0u; return; }

  float m0=bmin[0], m1=bmin[1], m2=bmin[2];
  float M0=bmax[0], M1=bmax[1], M2=bmax[2];
  float c0 = fminf(fmaxf((xyz[3*p  ]-m0)/(M0-m0),0.f),1.f);
  float c1 = fminf(fmaxf((xyz[3*p+1]-m1)/(M1-m1),0.f),1.f);
  float c2 = fminf(fmaxf((xyz[3*p+2]-m2)/(M2-m2),0.f),1.f);
  float c3 = fminf(fmaxf(timep[p],0.f),1.f);

  float sc = (float)(16<<lv) - 1.0f;
  float pos0 = c0*sc + 0.5f, pos1 = c1*sc + 0.5f;
  float pos2 = c2*sc + 0.5f, pos3 = c3*sc + 0.5f;
  float f0 = floorf(pos0), f1 = floorf(pos1), f2 = floorf(pos2), f3 = floorf(pos3);
  float w0 = pos0-f0, w1 = pos1-f1, w2 = pos2-f2, w3 = pos3-f3;
  unsigned i0 = (unsigned)f0, i1 = (unsigned)f1, i2 = (unsigned)f2, i3 = (unsigned)f3;
  unsigned hy0 = i1*2654435761u,     hy1 = hy0 + 2654435761u;
  unsigned hz0 = i2*805459861u,      hz1 = hz0 + 805459861u;
  unsigned ht0 = i3*3674653429u,     ht1 = ht0 + 3674653429u;
  float u0=1.f-w0, u1=1.f-w1, u2=1.f-w2, u3=1.f-w3;
  float a0 = 0.f, a1 = 0.f;
  if(BT){
    const unsigned* tb = (const unsigned*)tab + ((size_t)lv<<LOG2T);
    unsigned d = i0 ^ (i0 + 1u);
    unsigned rh[8], va[8], vb[8];
    #pragma unroll
    for(int cc=0;cc<8;cc++){
      unsigned r = ((cc&1)?hy1:hy0) ^ ((cc&2)?hz1:hz0) ^ ((cc&4)?ht1:ht0);
      rh[cc] = r;
      unsigned h0 = (i0 ^ r) & (TSIZE-1u);
      uint4 qd = *(const uint4*)(tb + (h0 & ~3u));
      unsigned e0 = h0 & 3u;
      va[cc] = qsel(qd, e0);
      vb[cc] = qsel(qd, e0 ^ (d & 3u));   // valid when d<=3
    }
    if(d > 3u){
      unsigned i0p = i0 + 1u;
      #pragma unroll
      for(int cc=0;cc<8;cc++)
        vb[cc] = tb[(i0p ^ rh[cc]) & (TSIZE-1u)];
    }
    float wyz[4] = {u1*u2, w1*u2, u1*w2, w1*w2};
    #pragma unroll
    for(int cc=0;cc<8;cc++){
      float wr = wyz[cc&3] * ((cc&4)? w3 : u3);
      float wa = u0*wr, wb = w0*wr;
      a0 = fmaf(bf_lo(va[cc]), wa, a0);
      a1 = fmaf(bf_hi(va[cc]), wa, a1);
      a0 = fmaf(bf_lo(vb[cc]), wb, a0);
      a1 = fmaf(bf_hi(vb[cc]), wb, a1);
    }
  } else {
    unsigned hx0 = i0, hx1 = i0 + 1u;
    float wxy[4] = {u0*u1, w0*u1, u0*w1, w0*w1};
    float wzt[4] = {u2*u3, w2*u3, u2*w3, w2*w3};
    const float* tb = (const float*)tab + ((size_t)lv<<(LOG2T+1));
    float2 v[16];
    #pragma unroll
    for(int cc=0;cc<16;cc++){
      unsigned h = ((cc&1)?hx1:hx0) ^ ((cc&2)?hy1:hy0) ^ ((cc&4)?hz1:hz0) ^ ((cc&8)?ht1:ht0);
      v[cc] = *(const float2*)(tb + ((size_t)(h&(TSIZE-1u))<<1));
    }
    #pragma unroll
    for(int cc=0;cc<16;cc++){
      float wc = wxy[cc&3]*wzt[cc>>2];
      a0 = fmaf(v[cc].x, wc, a0);
      a1 = fmaf(v[cc].y, wc, a1);
    }
  }
  enc_t[oidx] = (unsigned)f2bf(a0) | ((unsigned)f2bf(a1)<<16);
}

// ================= register MLP, lane-local activation handoff ===============
// Swapped operands: mfma(A=W', B=X). tau-scrambled K makes C->B pure VALU:
// B reg kt word t = cvt_pk(relu(acc[2kt][t]), relu(acc[2kt+1][t])). No bpermute.
__device__ __forceinline__ void pack_local(const f32x4* acc, bf16x8* out){
  #pragma unroll
  for(int kt=0;kt<2;kt++){
    unsigned w[4];
    #pragma unroll
    for(int t=0;t<4;t++){
      float x = fmaxf(acc[2*kt  ][t], 0.f);
      float y = fmaxf(acc[2*kt+1][t], 0.f);
      asm("v_cvt_pk_bf16_f32 %0, %1, %2" : "=v"(w[t]) : "v"(x), "v"(y));
    }
    out[kt] = __builtin_bit_cast(bf16x8, uint4{w[0],w[1],w[2],w[3]});
  }
}

// stem: enc -> hidden B-frag (LDS weights at smem+0 / smem+4096)
__device__ __forceinline__ void stem(const unsigned* __restrict__ enc_t,
                                     const char* smem, int p, int lane, int q,
                                     bf16x8* bh){
  uint4 e;
  e.x = enc_t[(size_t)(4*q+0)*NROWS + p];
  e.y = enc_t[(size_t)(4*q+1)*NROWS + p];
  e.z = enc_t[(size_t)(4*q+2)*NROWS + p];
  e.w = enc_t[(size_t)(4*q+3)*NROWS + p];
  bf16x8 b0 = __builtin_bit_cast(bf16x8, e);

  f32x4 acc[4];
  const bf16x8* wf0 = (const bf16x8*)(smem + 0);
  #pragma unroll
  for(int mt=0;mt<4;mt++)
    acc[mt] = __builtin_amdgcn_mfma_f32_16x16x32_bf16(wf0[mt*64+lane], b0,
                                                      f32x4{0.f,0.f,0.f,0.f}, 0,0,0);
  bf16x8 bt[2];
  pack_local(acc, bt);

  const bf16x8* wf1 = (const bf16x8*)(smem + 4096);
  #pragma unroll
  for(int mt=0;mt<4;mt++){
    f32x4 a = f32x4{0.f,0.f,0.f,0.f};
    #pragma unroll
    for(int kt=0;kt<2;kt++)
      a = __builtin_amdgcn_mfma_f32_16x16x32_bf16(wf1[(kt*4+mt)*64+lane], bt[kt], a, 0,0,0);
    acc[mt] = a;
  }
  pack_local(acc, bh);
}

template<int MT>
__device__ __forceinline__ void head_tail(const bf16x8* bh, const char* hb,
    const float* __restrict__ resid, float* __restrict__ outp, int od,
    int p, int q, int lane, float m){
  f32x4 acc[4];
  const bf16x8* w0 = (const bf16x8*)hb;
  #pragma unroll
  for(int mt=0;mt<4;mt++){
    f32x4 a = f32x4{0.f,0.f,0.f,0.f};
    #pragma unroll
    for(int kt=0;kt<2;kt++)
      a = __builtin_amdgcn_mfma_f32_16x16x32_bf16(w0[(kt*4+mt)*64+lane], bh[kt], a, 0,0,0);
    acc[mt] = a;
  }
  bf16x8 bx[2];
  pack_local(acc, bx);

  const bf16x8* w1 = (const bf16x8*)(hb + 8192);
  #pragma unroll
  for(int mt=0;mt<4;mt++){
    f32x4 a = f32x4{0.f,0.f,0.f,0.f};
    #pragma unroll
    for(int kt=0;kt<2;kt++)
      a = __builtin_amdgcn_mfma_f32_16x16x32_bf16(w1[(kt*4+mt)*64+lane], bx[kt], a, 0,0,0);
    acc[mt] = a;
  }
  bf16x8 by[2];
  pack_local(acc, by);

  const bf16x8* w2 = (const bf16x8*)(hb + 16384);
  f32x4 af[MT];
  #pragma unroll
  for(int mt=0;mt<MT;mt++){
    f32x4 a = f32x4{0.f,0.f,0.f,0.f};
    #pragma unroll
    for(int kt=0;kt<2;kt++)
      a = __builtin_amdgcn_mfma_f32_16x16x32_bf16(w2[(kt*MT+mt)*64+lane], by[kt], a, 0,0,0);
    af[mt] = a;
  }
  if(p < NPTS){
    #pragma unroll
    for(int mt=0;mt<MT;mt++){
      #pragma unroll
      for(int rr=0;rr<4;rr++){
        int n = 16*mt + 4*q + rr;
        if(n < od){
          size_t idx = (size_t)p*od + n;
          outp[idx] = resid[idx] + m*af[mt][rr];
        }
      }
    }
  }
}

// mlp kernel: 4 waves/block, 64 points/wave (4 sequential 16-pt batches);
// weights staged via 40KB LDS, reused by all batches -> staging traffic /4.
// Phase A: stem+xyz = [0,30720). B: scl+rot = [30720,67584). C: op+shs =
// [67584,108544). 4 x 40960 = exactly 160KB -> 4 blocks/CU.
__global__ __launch_bounds__(256,4) void mlp_k(
    const float* __restrict__ xyz, const float* __restrict__ scales,
    const float* __restrict__ rots, const float* __restrict__ opac,
    const float* __restrict__ shs,
    const float* __restrict__ bmin, const float* __restrict__ bmax,
    const unsigned* __restrict__ enc_t, const unsigned short* __restrict__ wsw,
    float* __restrict__ out)
{
  __shared__ __align__(16) char smem[40960];
  const int tid  = threadIdx.x;
  const int lane = tid & 63;
  const int wid  = blockIdx.x*4 + (tid>>6);
  const int pb   = wid*64;
  const int q = lane>>4, r = lane&15;

  float m0=bmin[0], m1=bmin[1], m2=bmin[2];
  float M0=bmax[0], M1=bmax[1], M2=bmax[2];
  int   pp[4];
  float mm[4];
  #pragma unroll
  for(int b=0;b<4;b++){
    int p = pb + 16*b + r;
    pp[b] = p;
    float m = 0.f;
    if(p < NPTS){
      float c0 = (xyz[3*p  ]-m0)/(M0-m0);
      float c1 = (xyz[3*p+1]-m1)/(M1-m1);
      float c2 = (xyz[3*p+2]-m2)/(M2-m2);
      m = (c0>=0.f && c0<=1.f && c1>=0.f && c1<=1.f && c2>=0.f && c2<=1.f) ? 1.f : 0.f;
    }
    mm[b] = m;
  }

  const char* wsb = (const char*)wsw;
  uint4* s4 = (uint4*)smem;

  // ---- phase A: stage stem + xyz  (1920 uint4) ----
  {
    const uint4* src = (const uint4*)(wsb + 0);
    #pragma unroll
    for(int i=0;i<8;i++){
      int idx = tid + 256*i;
      if(idx < 1920) s4[idx] = src[idx];
    }
  }
  __syncthreads();

  bf16x8 bh[4][2];
  #pragma unroll
  for(int b=0;b<4;b++)
    stem(enc_t, smem, pp[b], lane, q, bh[b]);

  #pragma unroll
  for(int b=0;b<4;b++)
    head_tail<1>(bh[b], smem+12288, xyz, out, 3, pp[b], q, lane, mm[b]);
  __syncthreads();

  // ---- phase B: stage scl + rot  (2304 uint4) ----
  {
    const uint4* src = (const uint4*)(wsb + 30720);
    #pragma unroll
    for(int i=0;i<9;i++) s4[tid + 256*i] = src[tid + 256*i];
  }
  __syncthreads();
  #pragma unroll
  for(int b=0;b<4;b++)
    head_tail<1>(bh[b], smem+0,     scales, out+(size_t)3*NPTS, 3, pp[b], q, lane, mm[b]);
  #pragma unroll
  for(int b=0;b<4;b++)
    head_tail<1>(bh[b], smem+18432, rots,   out+(size_t)6*NPTS, 4, pp[b], q, lane, mm[b]);
  __syncthreads();

  // ---- phase C: stage op + shs  (2560 uint4) ----
  {
    const uint4* src = (const uint4*)(wsb + 67584);
    #pragma unroll
    for(int i=0;i<10;i++) s4[tid + 256*i] = src[tid + 256*i];
  }
  __syncthreads();
  #pragma unroll
  for(int b=0;b<4;b++)
    head_tail<1>(bh[b], smem+0,     opac,   out+(size_t)10*NPTS, 1,  pp[b], q, lane, mm[b]);
  #pragma unroll
  for(int b=0;b<4;b++)
    head_tail<3>(bh[b], smem+18432, shs,    out+(size_t)11*NPTS, 48, pp[b], q, lane, mm[b]);
}

extern "C" void kernel_launch(void* const* d_in, const int* in_sizes, int n_in,
                              void* d_out, int out_size, void* d_ws, size_t ws_size,
                              hipStream_t stream){
  (void)in_sizes; (void)n_in; (void)out_size;
  WP wp;
  for(int i=0;i<17;i++) wp.p[i] = (const float*)d_in[9+i];
  char* ws = (char*)d_ws;
  unsigned short* wsw = (unsigned short*)ws;

  const size_t TAB_OFF   = 131072;
  const size_t TAB_BYTES = (size_t)(16u<<LOG2T) * 4;   // 32 MB packed bf16
  const size_t ENC_BYTES = (size_t)16 * NROWS * 4;     // 19.2 MB transposed enc
  bool bf16tab = ws_size >= TAB_OFF + TAB_BYTES + ENC_BYTES;
  size_t enc_off = bf16tab ? (TAB_OFF + TAB_BYTES) : TAB_OFF;
  unsigned* encp = (unsigned*)(ws + enc_off);

  const float* table = (const float*)d_in[8];
  unsigned* tabp = bf16tab ? (unsigned*)(ws + TAB_OFF) : nullptr;

  prep_all<<<4160,256,0,stream>>>(wp, wsw, table, tabp);

  unsigned enc_blocks = 16u * BLKS_PER_LV;
  if(bf16tab){
    encode_lv<true><<<enc_blocks,256,0,stream>>>(
        (const float*)d_in[0], (const float*)d_in[5],
        (const float*)d_in[6], (const float*)d_in[7], tabp, encp);
  } else {
    encode_lv<false><<<enc_blocks,256,0,stream>>>(
        (const float*)d_in[0], (const float*)d_in[5],
        (const float*)d_in[6], (const float*)d_in[7], table, encp);
  }

  mlp_k<<<NROWS/256, 256, 0, stream>>>(
      (const float*)d_in[0], (const float*)d_in[1], (const float*)d_in[2],
      (const float*)d_in[3], (const float*)d_in[4],
      (const float*)d_in[6], (const float*)d_in[7],
      encp, wsw, (float*)d_out);
}

// Round 14
// 279.976 us; speedup vs baseline: 1.1079x; 1.1079x over previous
//
#include <hip/hip_runtime.h>

#define NPTS 300000
#define LOG2T 19
#define TSIZE (1u<<LOG2T)
#define NROWS 300032u          // = 1172 * 256
#define BLKS_PER_LV 1172u

typedef float f32x4 __attribute__((ext_vector_type(4)));
typedef __bf16 bf16x8 __attribute__((ext_vector_type(8)));

__device__ __forceinline__ unsigned short f2bf(float f){
  unsigned u = __builtin_bit_cast(unsigned, f);
  u += 0x7fffu + ((u>>16)&1u);          // round-to-nearest-even
  return (unsigned short)(u>>16);
}
__device__ __forceinline__ float bf_lo(unsigned v){ return __builtin_bit_cast(float, v<<16); }
__device__ __forceinline__ float bf_hi(unsigned v){ return __builtin_bit_cast(float, v&0xffff0000u); }

__device__ __forceinline__ unsigned qsel(uint4 q, unsigned i){
  unsigned lo = (i&1u) ? q.y : q.x;
  unsigned hi = (i&1u) ? q.w : q.z;
  return (i&2u) ? hi : lo;
}

// tau-scramble of the K dimension: makes the C->B fragment handoff lane-local.
// B slot (kt,q,t,j) consumes K-row 32kt+8q+2t+j; C slot (mt,q,rr) produces
// neuron 16mt+4q+rr. tau(32kt+8q+2t+j) = 16(2kt+j)+4q+t aligns them.
__device__ __forceinline__ int tau(int k){
  return 16*(2*(k>>5) + (k&1)) + 4*((k>>3)&3) + ((k>>1)&3);
}

// ---------------- prep: weights f32->bf16 frags + table f32->packed bf16 -----
struct WP { const float* p[17]; };

__device__ const int LK[17]  = {32,64, 64,64,64, 64,64,64, 64,64,64, 64,64,64, 64,64,64};
__device__ const int LN[17]  = {64,64, 64,64, 3, 64,64, 3, 64,64, 4, 64,64, 1, 64,64,48};
__device__ const int LNT[17] = { 4, 4,  4, 4, 1,  4, 4, 1,  4, 4, 1,  4, 4, 1,  4, 4, 3};
__device__ const int LOFF[17]= {0,4096, 12288,20480,28672, 30720,38912,47104,
                                49152,57344,65536, 67584,75776,83968, 86016,94208,102400};

__global__ void prep_all(WP wp, unsigned short* wdst,
                         const float* __restrict__ t, unsigned* __restrict__ tdst){
  int gtid = blockIdx.x*blockDim.x + threadIdx.x;
  int gstr = blockDim.x*gridDim.x;
  if(tdst){
    int n = (16 << LOG2T) / 2;  // 4M float4 -> uint2
    for(int i=gtid; i<n; i+=gstr){
      float4 f = ((const float4*)t)[i];
      uint2 o;
      o.x = (unsigned)f2bf(f.x) | ((unsigned)f2bf(f.y)<<16);
      o.y = (unsigned)f2bf(f.z) | ((unsigned)f2bf(f.w)<<16);
      ((uint2*)tdst)[i] = o;
    }
  }
  for(int layer=0; layer<17; layer++){
    const float* W = wp.p[layer];
    int K = LK[layer], Nn = LN[layer], NT = LNT[layer];
    unsigned short* d = wdst + LOFF[layer]/2;
    int nel = (K/32) * NT * 512;
    for(int i=gtid; i<nel; i += gstr){
      int j = i & 7, l = (i>>3)&63, fidx = i>>9;
      int kt = fidx / NT, nt = fidx - kt*NT;
      int k = kt*32 + ((l>>4)<<3) + j;
      if(layer != 0) k = tau(k);          // K-scramble (all K=64 layers)
      int n = nt*16 + (l&15);
      unsigned short v = 0;
      if(n < Nn) v = f2bf(W[k*Nn + n]);
      d[i] = v;
    }
  }
}

// ---------------- encode: one thread per (point, level), level-major blocks --
// quad x-pair trick (PRIMES[0]==1): h1 = h0 ^ d with d = i0^(i0+1); when d<=3
// (75% of i0) both x-corners live in one aligned uint4 -> 8 quad loads; only
// i0 % 4 == 3 lanes issue the 8 scalar fallbacks. ~10 requests vs 16 naive.
template<bool BT>
__global__ __launch_bounds__(256) void encode_lv(
    const float* __restrict__ xyz, const float* __restrict__ timep,
    const float* __restrict__ bmin, const float* __restrict__ bmax,
    const void* __restrict__ tab, unsigned* __restrict__ enc_t)
{
  unsigned bid = blockIdx.x;
  unsigned lv = bid / BLKS_PER_LV;
  unsigned p = (bid - lv*BLKS_PER_LV)*256u + threadIdx.x;
  size_t oidx = (size_t)lv*NROWS + p;
  if(p >= NPTS){ enc_t[oidx] = 0u; return; }

  float m0=bmin[0], m1=bmin[1], m2=bmin[2];
  float M0=bmax[0], M1=bmax[1], M2=bmax[2];
  float c0 = fminf(fmaxf((xyz[3*p  ]-m0)/(M0-m0),0.f),1.f);
  float c1 = fminf(fmaxf((xyz[3*p+1]-m1)/(M1-m1),0.f),1.f);
  float c2 = fminf(fmaxf((xyz[3*p+2]-m2)/(M2-m2),0.f),1.f);
  float c3 = fminf(fmaxf(timep[p],0.f),1.f);

  float sc = (float)(16<<lv) - 1.0f;
  float pos0 = c0*sc + 0.5f, pos1 = c1*sc + 0.5f;
  float pos2 = c2*sc + 0.5f, pos3 = c3*sc + 0.5f;
  float f0 = floorf(pos0), f1 = floorf(pos1), f2 = floorf(pos2), f3 = floorf(pos3);
  float w0 = pos0-f0, w1 = pos1-f1, w2 = pos2-f2, w3 = pos3-f3;
  unsigned i0 = (unsigned)f0, i1 = (unsigned)f1, i2 = (unsigned)f2, i3 = (unsigned)f3;
  unsigned hy0 = i1*2654435761u,     hy1 = hy0 + 2654435761u;
  unsigned hz0 = i2*805459861u,      hz1 = hz0 + 805459861u;
  unsigned ht0 = i3*3674653429u,     ht1 = ht0 + 3674653429u;
  float u0=1.f-w0, u1=1.f-w1, u2=1.f-w2, u3=1.f-w3;
  float a0 = 0.f, a1 = 0.f;
  if(BT){
    const unsigned* tb = (const unsigned*)tab + ((size_t)lv<<LOG2T);
    unsigned d = i0 ^ (i0 + 1u);
    unsigned rh[8], va[8], vb[8];
    #pragma unroll
    for(int cc=0;cc<8;cc++){
      unsigned r = ((cc&1)?hy1:hy0) ^ ((cc&2)?hz1:hz0) ^ ((cc&4)?ht1:ht0);
      rh[cc] = r;
      unsigned h0 = (i0 ^ r) & (TSIZE-1u);
      uint4 qd = *(const uint4*)(tb + (h0 & ~3u));
      unsigned e0 = h0 & 3u;
      va[cc] = qsel(qd, e0);
      vb[cc] = qsel(qd, e0 ^ (d & 3u));   // valid when d<=3
    }
    if(d > 3u){
      unsigned i0p = i0 + 1u;
      #pragma unroll
      for(int cc=0;cc<8;cc++)
        vb[cc] = tb[(i0p ^ rh[cc]) & (TSIZE-1u)];
    }
    float wyz[4] = {u1*u2, w1*u2, u1*w2, w1*w2};
    #pragma unroll
    for(int cc=0;cc<8;cc++){
      float wr = wyz[cc&3] * ((cc&4)? w3 : u3);
      float wa = u0*wr, wb = w0*wr;
      a0 = fmaf(bf_lo(va[cc]), wa, a0);
      a1 = fmaf(bf_hi(va[cc]), wa, a1);
      a0 = fmaf(bf_lo(vb[cc]), wb, a0);
      a1 = fmaf(bf_hi(vb[cc]), wb, a1);
    }
  } else {
    unsigned hx0 = i0, hx1 = i0 + 1u;
    float wxy[4] = {u0*u1, w0*u1, u0*w1, w0*w1};
    float wzt[4] = {u2*u3, w2*u3, u2*w3, w2*w3};
    const float* tb = (const float*)tab + ((size_t)lv<<(LOG2T+1));
    float2 v[16];
    #pragma unroll
    for(int cc=0;cc<16;cc++){
      unsigned h = ((cc&1)?hx1:hx0) ^ ((cc&2)?hy1:hy0) ^ ((cc&4)?hz1:hz0) ^ ((cc&8)?ht1:ht0);
      v[cc] = *(const float2*)(tb + ((size_t)(h&(TSIZE-1u))<<1));
    }
    #pragma unroll
    for(int cc=0;cc<16;cc++){
      float wc = wxy[cc&3]*wzt[cc>>2];
      a0 = fmaf(v[cc].x, wc, a0);
      a1 = fmaf(v[cc].y, wc, a1);
    }
  }
  enc_t[oidx] = (unsigned)f2bf(a0) | ((unsigned)f2bf(a1)<<16);
}

// ================= register MLP, lane-local activation handoff ===============
// Swapped operands: mfma(A=W', B=X). tau-scrambled K makes C->B pure VALU:
// B reg kt word t = cvt_pk(relu(acc[2kt][t]), relu(acc[2kt+1][t])). No bpermute.
__device__ __forceinline__ void pack_local(const f32x4* acc, bf16x8* out){
  #pragma unroll
  for(int kt=0;kt<2;kt++){
    unsigned w[4];
    #pragma unroll
    for(int t=0;t<4;t++){
      float x = fmaxf(acc[2*kt  ][t], 0.f);
      float y = fmaxf(acc[2*kt+1][t], 0.f);
      asm("v_cvt_pk_bf16_f32 %0, %1, %2" : "=v"(w[t]) : "v"(x), "v"(y));
    }
    out[kt] = __builtin_bit_cast(bf16x8, uint4{w[0],w[1],w[2],w[3]});
  }
}

// stem: enc -> hidden B-frag (LDS weights at smem+0 / smem+4096)
__device__ __forceinline__ void stem(const unsigned* __restrict__ enc_t,
                                     const char* smem, int p, int lane, int q,
                                     bf16x8* bh){
  uint4 e;
  e.x = enc_t[(size_t)(4*q+0)*NROWS + p];
  e.y = enc_t[(size_t)(4*q+1)*NROWS + p];
  e.z = enc_t[(size_t)(4*q+2)*NROWS + p];
  e.w = enc_t[(size_t)(4*q+3)*NROWS + p];
  bf16x8 b0 = __builtin_bit_cast(bf16x8, e);

  f32x4 acc[4];
  const bf16x8* wf0 = (const bf16x8*)(smem + 0);
  #pragma unroll
  for(int mt=0;mt<4;mt++)
    acc[mt] = __builtin_amdgcn_mfma_f32_16x16x32_bf16(wf0[mt*64+lane], b0,
                                                      f32x4{0.f,0.f,0.f,0.f}, 0,0,0);
  bf16x8 bt[2];
  pack_local(acc, bt);

  const bf16x8* wf1 = (const bf16x8*)(smem + 4096);
  #pragma unroll
  for(int mt=0;mt<4;mt++){
    f32x4 a = f32x4{0.f,0.f,0.f,0.f};
    #pragma unroll
    for(int kt=0;kt<2;kt++)
      a = __builtin_amdgcn_mfma_f32_16x16x32_bf16(wf1[(kt*4+mt)*64+lane], bt[kt], a, 0,0,0);
    acc[mt] = a;
  }
  pack_local(acc, bh);
}

template<int MT>
__device__ __forceinline__ void head_tail(const bf16x8* bh, const char* hb,
    const float* __restrict__ resid, float* __restrict__ outp, int od,
    int p, int q, int lane, float m){
  f32x4 acc[4];
  const bf16x8* w0 = (const bf16x8*)hb;
  #pragma unroll
  for(int mt=0;mt<4;mt++){
    f32x4 a = f32x4{0.f,0.f,0.f,0.f};
    #pragma unroll
    for(int kt=0;kt<2;kt++)
      a = __builtin_amdgcn_mfma_f32_16x16x32_bf16(w0[(kt*4+mt)*64+lane], bh[kt], a, 0,0,0);
    acc[mt] = a;
  }
  bf16x8 bx[2];
  pack_local(acc, bx);

  const bf16x8* w1 = (const bf16x8*)(hb + 8192);
  #pragma unroll
  for(int mt=0;mt<4;mt++){
    f32x4 a = f32x4{0.f,0.f,0.f,0.f};
    #pragma unroll
    for(int kt=0;kt<2;kt++)
      a = __builtin_amdgcn_mfma_f32_16x16x32_bf16(w1[(kt*4+mt)*64+lane], bx[kt], a, 0,0,0);
    acc[mt] = a;
  }
  bf16x8 by[2];
  pack_local(acc, by);

  const bf16x8* w2 = (const bf16x8*)(hb + 16384);
  f32x4 af[MT];
  #pragma unroll
  for(int mt=0;mt<MT;mt++){
    f32x4 a = f32x4{0.f,0.f,0.f,0.f};
    #pragma unroll
    for(int kt=0;kt<2;kt++)
      a = __builtin_amdgcn_mfma_f32_16x16x32_bf16(w2[(kt*MT+mt)*64+lane], by[kt], a, 0,0,0);
    af[mt] = a;
  }
  if(p < NPTS){
    #pragma unroll
    for(int mt=0;mt<MT;mt++){
      #pragma unroll
      for(int rr=0;rr<4;rr++){
        int n = 16*mt + 4*q + rr;
        if(n < od){
          size_t idx = (size_t)p*od + n;
          outp[idx] = resid[idx] + m*af[mt][rr];
        }
      }
    }
  }
}

// mlp kernel: 4 waves/block, 32 points/wave (2 sequential 16-pt batches);
// weights staged via 40KB LDS, reused by both batches -> staging traffic /2.
// Phase A: stem+xyz = [0,30720). B: scl+rot = [30720,67584). C: op+shs =
// [67584,108544). 4 x 40960 = exactly 160KB -> 4 blocks/CU.
// NOTE: batch depth 2 is the measured optimum (1:287, 2:281, 4:310 us) —
// beyond 2, bh[] + point-state VGPR pressure breaks 4 blocks/CU.
__global__ __launch_bounds__(256,4) void mlp_k(
    const float* __restrict__ xyz, const float* __restrict__ scales,
    const float* __restrict__ rots, const float* __restrict__ opac,
    const float* __restrict__ shs,
    const float* __restrict__ bmin, const float* __restrict__ bmax,
    const unsigned* __restrict__ enc_t, const unsigned short* __restrict__ wsw,
    float* __restrict__ out)
{
  __shared__ __align__(16) char smem[40960];
  const int tid  = threadIdx.x;
  const int lane = tid & 63;
  const int wid  = blockIdx.x*4 + (tid>>6);
  const int pb   = wid*32;
  const int q = lane>>4, r = lane&15;
  const int pA = pb + r, pB = pb + 16 + r;

  float m0=bmin[0], m1=bmin[1], m2=bmin[2];
  float M0=bmax[0], M1=bmax[1], M2=bmax[2];
  float mA = 0.f, mB = 0.f;
  if(pA < NPTS){
    float c0 = (xyz[3*pA  ]-m0)/(M0-m0);
    float c1 = (xyz[3*pA+1]-m1)/(M1-m1);
    float c2 = (xyz[3*pA+2]-m2)/(M2-m2);
    mA = (c0>=0.f && c0<=1.f && c1>=0.f && c1<=1.f && c2>=0.f && c2<=1.f) ? 1.f : 0.f;
  }
  if(pB < NPTS){
    float c0 = (xyz[3*pB  ]-m0)/(M0-m0);
    float c1 = (xyz[3*pB+1]-m1)/(M1-m1);
    float c2 = (xyz[3*pB+2]-m2)/(M2-m2);
    mB = (c0>=0.f && c0<=1.f && c1>=0.f && c1<=1.f && c2>=0.f && c2<=1.f) ? 1.f : 0.f;
  }

  const char* wsb = (const char*)wsw;
  uint4* s4 = (uint4*)smem;

  // ---- phase A: stage stem + xyz  (1920 uint4) ----
  {
    const uint4* src = (const uint4*)(wsb + 0);
    #pragma unroll
    for(int i=0;i<8;i++){
      int idx = tid + 256*i;
      if(idx < 1920) s4[idx] = src[idx];
    }
  }
  __syncthreads();

  bf16x8 bhA[2], bhB[2];
  stem(enc_t, smem, pA, lane, q, bhA);
  stem(enc_t, smem, pB, lane, q, bhB);

  head_tail<1>(bhA, smem+12288, xyz,    out,                 3, pA,q,lane, mA);
  head_tail<1>(bhB, smem+12288, xyz,    out,                 3, pB,q,lane, mB);
  __syncthreads();

  // ---- phase B: stage scl + rot  (2304 uint4) ----
  {
    const uint4* src = (const uint4*)(wsb + 30720);
    #pragma unroll
    for(int i=0;i<9;i++) s4[tid + 256*i] = src[tid + 256*i];
  }
  __syncthreads();
  head_tail<1>(bhA, smem+0,     scales, out+(size_t)3*NPTS,  3, pA,q,lane, mA);
  head_tail<1>(bhB, smem+0,     scales, out+(size_t)3*NPTS,  3, pB,q,lane, mB);
  head_tail<1>(bhA, smem+18432, rots,   out+(size_t)6*NPTS,  4, pA,q,lane, mA);
  head_tail<1>(bhB, smem+18432, rots,   out+(size_t)6*NPTS,  4, pB,q,lane, mB);
  __syncthreads();

  // ---- phase C: stage op + shs  (2560 uint4) ----
  {
    const uint4* src = (const uint4*)(wsb + 67584);
    #pragma unroll
    for(int i=0;i<10;i++) s4[tid + 256*i] = src[tid + 256*i];
  }
  __syncthreads();
  head_tail<1>(bhA, smem+0,     opac,   out+(size_t)10*NPTS, 1, pA,q,lane, mA);
  head_tail<1>(bhB, smem+0,     opac,   out+(size_t)10*NPTS, 1, pB,q,lane, mB);
  head_tail<3>(bhA, smem+18432, shs,    out+(size_t)11*NPTS, 48, pA,q,lane, mA);
  head_tail<3>(bhB, smem+18432, shs,    out+(size_t)11*NPTS, 48, pB,q,lane, mB);
}

extern "C" void kernel_launch(void* const* d_in, const int* in_sizes, int n_in,
                              void* d_out, int out_size, void* d_ws, size_t ws_size,
                              hipStream_t stream){
  (void)in_sizes; (void)n_in; (void)out_size;
  WP wp;
  for(int i=0;i<17;i++) wp.p[i] = (const float*)d_in[9+i];
  char* ws = (char*)d_ws;
  unsigned short* wsw = (unsigned short*)ws;

  const size_t TAB_OFF   = 131072;
  const size_t TAB_BYTES = (size_t)(16u<<LOG2T) * 4;   // 32 MB packed bf16
  const size_t ENC_BYTES = (size_t)16 * NROWS * 4;     // 19.2 MB transposed enc
  bool bf16tab = ws_size >= TAB_OFF + TAB_BYTES + ENC_BYTES;
  size_t enc_off = bf16tab ? (TAB_OFF + TAB_BYTES) : TAB_OFF;
  unsigned* encp = (unsigned*)(ws + enc_off);

  const float* table = (const float*)d_in[8];
  unsigned* tabp = bf16tab ? (unsigned*)(ws + TAB_OFF) : nullptr;

  prep_all<<<4160,256,0,stream>>>(wp, wsw, table, tabp);

  unsigned enc_blocks = 16u * BLKS_PER_LV;
  if(bf16tab){
    encode_lv<true><<<enc_blocks,256,0,stream>>>(
        (const float*)d_in[0], (const float*)d_in[5],
        (const float*)d_in[6], (const float*)d_in[7], tabp, encp);
  } else {
    encode_lv<false><<<enc_blocks,256,0,stream>>>(
        (const float*)d_in[0], (const float*)d_in[5],
        (const float*)d_in[6], (const float*)d_in[7], table, encp);
  }

  mlp_k<<<NROWS/128, 256, 0, stream>>>(
      (const float*)d_in[0], (const float*)d_in[1], (const float*)d_in[2],
      (const float*)d_in[3], (const float*)d_in[4],
      (const float*)d_in[6], (const float*)d_in[7],
      encp, wsw, (float*)d_out);
}